// Round 7
// baseline (66.021 us; speedup 1.0000x reference)
//
#include <hip/hip_runtime.h>

#define NV 5000
#define NF 1000
#define HH 256
#define NTILE 256          // 16x16 tiles of 16x16 pixels
#define TCUT 25.0f         // exp2 cutoff: prob < 2^-25 -> negligible

// ---------------- kernel 1: vertex transform + projection (VERBATIM math) --
__global__ void k_prep_vertex(const float* __restrict__ vtx,
                              const float* __restrict__ cam,
                              float* __restrict__ out,
                              float2* __restrict__ xy) {
    int i = blockIdx.x * blockDim.x + threadIdx.x;
    if (i == 0) { out[0] = 0.0f; }
    if (i >= NV) return;
    float ex = cam[0], ey = cam[1], ez = cam[2];
    // z_ax = normalize(-eye)
    float zn = sqrtf(ex*ex + ey*ey + ez*ez) + 1e-8f;
    float zx = -ex/zn, zy = -ey/zn, zz = -ez/zn;
    // x_ax = normalize(cross((0,1,0), z)) = normalize((zz, 0, -zx))
    float xn = sqrtf(zz*zz + zx*zx) + 1e-8f;
    float xx = zz/xn, xy_ = 0.0f, xz = -zx/xn;
    // y_ax = cross(z, x)
    float yx = zy*xz - zz*xy_;
    float yy = zz*xx - zx*xz;
    float yz = zx*xy_ - zy*xx;
    float vx = vtx[i*3+0]-ex, vy = vtx[i*3+1]-ey, vz = vtx[i*3+2]-ez;
    float cxx = vx*xx + vy*xy_ + vz*xz;
    float cyy = vx*yx + vy*yy  + vz*yz;
    float czz = vx*zx + vy*zy  + vz*zz;
    const float w = 0.5773502691896258f;   // tan(30 deg)
    float den = czz*w + 1e-8f;
    xy[i] = make_float2(cxx/den, cyy/den);
}

// ---------------- kernel 2: per-face edge coefficients (VERBATIM) ----------
__global__ void k_face(const int* __restrict__ faces,
                       const float2* __restrict__ xy,
                       float4* __restrict__ a4,
                       float4* __restrict__ b4,
                       float* __restrict__ c1) {
    int f = blockIdx.x * blockDim.x + threadIdx.x;
    if (f >= NF) return;
    int i0 = faces[f*3+0], i1 = faces[f*3+1], i2 = faces[f*3+2];
    float2 p0 = xy[i0], p1 = xy[i1], p2 = xy[i2];
    float eax = p1.x-p0.x, eay = p1.y-p0.y;
    float ebx = p2.x-p0.x, eby = p2.y-p0.y;
    float cr = eax*eby - eay*ebx;
    float s = (cr > 0.0f) ? 1.0f : ((cr < 0.0f) ? -1.0f : 0.0f);
    const float m = -144.26950408889634f * s;   // -log2(e)/SHARP * orient

    float A0,B0,C0,A1,B1,C1,A2,B2,C2;
    {   // edge 0: p0 -> p1
        float ex_ = p1.x-p0.x, ey_ = p1.y-p0.y;
        float el = sqrtf(ex_*ex_+ey_*ey_) + 1e-8f;
        A0 = (ex_/el)*m; B0 = (-ey_/el)*m; C0 = ((ey_*p0.x - ex_*p0.y)/el)*m;
    }
    {   // edge 1: p1 -> p2
        float ex_ = p2.x-p1.x, ey_ = p2.y-p1.y;
        float el = sqrtf(ex_*ex_+ey_*ey_) + 1e-8f;
        A1 = (ex_/el)*m; B1 = (-ey_/el)*m; C1 = ((ey_*p1.x - ex_*p1.y)/el)*m;
    }
    {   // edge 2: p2 -> p0
        float ex_ = p0.x-p2.x, ey_ = p0.y-p2.y;
        float el = sqrtf(ex_*ex_+ey_*ey_) + 1e-8f;
        A2 = (ex_/el)*m; B2 = (-ey_/el)*m; C2 = ((ey_*p2.x - ex_*p2.y)/el)*m;
    }
    a4[f] = make_float4(A0, B0, C0, A1);
    b4[f] = make_float4(B1, C1, A2, B2);
    c1[f] = C2;
}

// ---- kernel 3: fused cull + compact + render + loss, one block per tile ----
__global__ __launch_bounds__(1024) void k_all(
        const float4* __restrict__ a4,
        const float4* __restrict__ b4,
        const float*  __restrict__ c1,
        const float*  __restrict__ ref,
        float* __restrict__ out) {
    __shared__ float4 sa[NF];
    __shared__ float4 sb[NF];
    __shared__ float  sc[NF];
    __shared__ int    wc[16];
    __shared__ int    cnt_s;
    __shared__ float  sacc[3*256];
    __shared__ float  wsum[4];

    const int t    = threadIdx.x;
    const int lane = t & 63;
    const int w    = t >> 6;
    const int tile = blockIdx.x;
    const int tx = tile & 15, ty = tile >> 4;
    const float s  = 2.0f / HH;
    const float cx = (tx*16 + 8) * s - 1.0f;
    const float cy = (ty*16 + 8) * s - 1.0f;
    const float h  = 7.5f * s;

    // ---- phase 1: cull (verbatim round-5/6 bound) + order-preserving compact
    bool keep = false;
    float4 qa = make_float4(0,0,0,0), qb = make_float4(0,0,0,0);
    float qc = 0.0f;
    if (t < NF) {
        qa = a4[t]; qb = b4[t]; qc = c1[t];
        float b0 = fmaf(qa.x, cy, fmaf(qa.y, cx, qa.z)) - (fabsf(qa.x)+fabsf(qa.y))*h;
        float b1 = fmaf(qa.w, cy, fmaf(qb.x, cx, qb.y)) - (fabsf(qa.w)+fabsf(qb.x))*h;
        float b2 = fmaf(qb.z, cy, fmaf(qb.w, cx, qc))   - (fabsf(qb.z)+fabsf(qb.w))*h;
        keep = (fmaxf(fmaxf(b0, b1), b2) <= TCUT);
    }
    unsigned long long m = __ballot(keep);
    if (lane == 0) wc[w] = __popcll(m);
    __syncthreads();
    int base = 0;
    for (int q = 0; q < w; ++q) base += wc[q];
    if (keep) {
        int pos = base + __popcll(m & ((1ull << lane) - 1ull));
        sa[pos] = qa; sb[pos] = qb; sc[pos] = qc;
    }
    if (t == 0) {
        int c = 0;
        #pragma unroll
        for (int q = 0; q < 16; ++q) c += wc[q];
        cnt_s = c;
    }
    __syncthreads();
    const int cnt = cnt_s;

    // ---- phase 2: render — 4 threads per pixel, slice strides the list -----
    const int p   = t & 255;
    const int sl  = t >> 8;
    const int col = tx*16 + (p & 15);
    const int row = ty*16 + (p >> 4);
    const float px = (col + 0.5f) * s - 1.0f;
    const float py = (row + 0.5f) * s - 1.0f;
    float acc = 0.0f;
    for (int k = sl; k < cnt; k += 4) {
        float4 fa = sa[k];
        float4 fb = sb[k];
        float  fc = sc[k];
        float t0 = fmaf(fa.x, py, fmaf(fa.y, px, fa.z));
        float t1 = fmaf(fa.w, py, fmaf(fb.x, px, fb.y));
        float t2 = fmaf(fb.z, py, fmaf(fb.w, px, fc));
        float tmax = fmaxf(fmaxf(t0, t1), t2);
        if (__any(tmax <= TCUT)) {
            float e0 = __builtin_amdgcn_exp2f(t0);
            float e1 = __builtin_amdgcn_exp2f(t1);
            float e2 = __builtin_amdgcn_exp2f(t2);
            float Pm = (1.0f+e0) * (1.0f+e1) * (1.0f+e2);
            float prob = __builtin_amdgcn_rcpf(Pm);
            float q = fmaxf(1.0f - prob, 1e-6f);
            acc += __builtin_amdgcn_logf(q);      // log2(1-prob)
        }
    }
    if (sl > 0) sacc[(sl-1)*256 + p] = acc;
    __syncthreads();

    // ---- phase 3: slice-reduce + loss + block-reduce -----------------------
    float sq = 0.0f;
    if (sl == 0) {
        float tot = acc + sacc[p] + sacc[256 + p] + sacc[512 + p];
        float sil = 1.0f - __builtin_amdgcn_exp2f(tot);   // 1 - exp(log_bg)
        float d = sil - ref[row*HH + col];
        sq = d * d;
    }
    #pragma unroll
    for (int off = 32; off > 0; off >>= 1)
        sq += __shfl_down(sq, off, 64);
    if (lane == 0 && w < 4) wsum[w] = sq;
    __syncthreads();
    if (t == 0)
        atomicAdd(out, wsum[0] + wsum[1] + wsum[2] + wsum[3]);
}

extern "C" void kernel_launch(void* const* d_in, const int* in_sizes, int n_in,
                              void* d_out, int out_size, void* d_ws, size_t ws_size,
                              hipStream_t stream) {
    const float* vtx   = (const float*)d_in[0];   // (1,5000,3) f32
    const int*   faces = (const int*)  d_in[1];   // (1,1000,3) i32
    const float* cam   = (const float*)d_in[2];   // (3,) f32
    const float* ref   = (const float*)d_in[3];   // (256,256) f32
    float* out = (float*)d_out;

    char* ws = (char*)d_ws;
    float2* xy = (float2*)(ws + 0);        // 40000 B
    float4* a4 = (float4*)(ws + 40448);    // 16000 B
    float4* b4 = (float4*)(ws + 56448);    // 16000 B
    float*  c1 = (float*) (ws + 72448);    //  4000 B

    k_prep_vertex<<<dim3((NV+255)/256), dim3(256),  0, stream>>>(vtx, cam, out, xy);
    k_face       <<<dim3((NF+255)/256), dim3(256),  0, stream>>>(faces, xy, a4, b4, c1);
    k_all        <<<dim3(NTILE),        dim3(1024), 0, stream>>>(a4, b4, c1, ref, out);
}

// Round 8
// 63.102 us; speedup vs baseline: 1.0463x; 1.0463x over previous
//
#include <hip/hip_runtime.h>

#define NV 5000
#define NF 1000
#define HH 256
#define NPIX (HH*HH)
#define NTILE 256          // 16x16 tiles of 16x16 pixels
#define CS 125             // faces per chunk
#define NCHK 8             // CS*NCHK = 1000 = NF exactly
#define TCUT 25.0f         // exp2 cutoff: prob < 2^-25 -> negligible

// ---------------- kernel 1: vertex transform + projection (VERBATIM r1) ----
__global__ void k_prep_vertex(const float* __restrict__ vtx,
                              const float* __restrict__ cam,
                              float* __restrict__ out,
                              unsigned* __restrict__ counter,
                              float2* __restrict__ xy) {
    int i = blockIdx.x * blockDim.x + threadIdx.x;
    if (i == 0) { out[0] = 0.0f; counter[0] = 0u; }
    if (i >= NV) return;
    float ex = cam[0], ey = cam[1], ez = cam[2];
    // z_ax = normalize(-eye)
    float zn = sqrtf(ex*ex + ey*ey + ez*ez) + 1e-8f;
    float zx = -ex/zn, zy = -ey/zn, zz = -ez/zn;
    // x_ax = normalize(cross((0,1,0), z)) = normalize((zz, 0, -zx))
    float xn = sqrtf(zz*zz + zx*zx) + 1e-8f;
    float xx = zz/xn, xy_ = 0.0f, xz = -zx/xn;
    // y_ax = cross(z, x)
    float yx = zy*xz - zz*xy_;
    float yy = zz*xx - zx*xz;
    float yz = zx*xy_ - zy*xx;
    float vx = vtx[i*3+0]-ex, vy = vtx[i*3+1]-ey, vz = vtx[i*3+2]-ez;
    float cxx = vx*xx + vy*xy_ + vz*xz;
    float cyy = vx*yx + vy*yy  + vz*yz;
    float czz = vx*zx + vy*zy  + vz*zz;
    const float w = 0.5773502691896258f;   // tan(30 deg)
    float den = czz*w + 1e-8f;
    xy[i] = make_float2(cxx/den, cyy/den);
}

// ---------------- kernel 2: per-face edge coefficients (VERBATIM r1) -------
__global__ void k_face(const int* __restrict__ faces,
                       const float2* __restrict__ xy,
                       float4* __restrict__ a4,
                       float4* __restrict__ b4,
                       float* __restrict__ c1) {
    int f = blockIdx.x * blockDim.x + threadIdx.x;
    if (f >= NF) return;
    int i0 = faces[f*3+0], i1 = faces[f*3+1], i2 = faces[f*3+2];
    float2 p0 = xy[i0], p1 = xy[i1], p2 = xy[i2];
    float eax = p1.x-p0.x, eay = p1.y-p0.y;
    float ebx = p2.x-p0.x, eby = p2.y-p0.y;
    float cr = eax*eby - eay*ebx;
    float s = (cr > 0.0f) ? 1.0f : ((cr < 0.0f) ? -1.0f : 0.0f);
    const float m = -144.26950408889634f * s;   // -log2(e)/SHARP * orient

    float A0,B0,C0,A1,B1,C1,A2,B2,C2;
    {   // edge 0: p0 -> p1
        float ex_ = p1.x-p0.x, ey_ = p1.y-p0.y;
        float el = sqrtf(ex_*ex_+ey_*ey_) + 1e-8f;
        A0 = (ex_/el)*m; B0 = (-ey_/el)*m; C0 = ((ey_*p0.x - ex_*p0.y)/el)*m;
    }
    {   // edge 1: p1 -> p2
        float ex_ = p2.x-p1.x, ey_ = p2.y-p1.y;
        float el = sqrtf(ex_*ex_+ey_*ey_) + 1e-8f;
        A1 = (ex_/el)*m; B1 = (-ey_/el)*m; C1 = ((ey_*p1.x - ex_*p1.y)/el)*m;
    }
    {   // edge 2: p2 -> p0
        float ex_ = p0.x-p2.x, ey_ = p0.y-p2.y;
        float el = sqrtf(ex_*ex_+ey_*ey_) + 1e-8f;
        A2 = (ex_/el)*m; B2 = (-ey_/el)*m; C2 = ((ey_*p2.x - ex_*p2.y)/el)*m;
    }
    a4[f] = make_float4(A0, B0, C0, A1);
    b4[f] = make_float4(B1, C1, A2, B2);
    c1[f] = C2;
}

// ---- kernel 3: fused per-chunk cull + render, one (tile,chunk) per block ---
__global__ __launch_bounds__(256) void k_render(
        const float4* __restrict__ a4,
        const float4* __restrict__ b4,
        const float*  __restrict__ c1,
        float* __restrict__ part) {
    __shared__ float4 sa[CS];
    __shared__ float4 sb[CS];
    __shared__ float  sc[CS];
    __shared__ int    wc[2];
    __shared__ int    cnt_s;

    const int tile = blockIdx.x;
    const int c    = blockIdx.y;
    const int t    = threadIdx.x;
    const int lane = t & 63;
    const int w    = t >> 6;

    const int tx = tile & 15, ty = tile >> 4;
    const float s  = 2.0f / HH;
    const float cx = (tx*16 + 8) * s - 1.0f;
    const float cy = (ty*16 + 8) * s - 1.0f;
    const float h  = 7.5f * s;

    // cull faces [c*CS, c*CS+CS) with the verbatim round-5/6 conservative bound
    bool keep = false;
    float4 qa = make_float4(0,0,0,0), qb = make_float4(0,0,0,0);
    float  qc = 0.0f;
    if (t < CS) {
        int f = c*CS + t;
        qa = a4[f]; qb = b4[f]; qc = c1[f];
        float b0 = fmaf(qa.x, cy, fmaf(qa.y, cx, qa.z)) - (fabsf(qa.x)+fabsf(qa.y))*h;
        float b1 = fmaf(qa.w, cy, fmaf(qb.x, cx, qb.y)) - (fabsf(qa.w)+fabsf(qb.x))*h;
        float b2 = fmaf(qb.z, cy, fmaf(qb.w, cx, qc))   - (fabsf(qb.z)+fabsf(qb.w))*h;
        keep = (fmaxf(fmaxf(b0, b1), b2) <= TCUT);
    }
    unsigned long long m = __ballot(keep);        // only waves 0,1 can keep
    if (lane == 0 && w < 2) wc[w] = __popcll(m);
    __syncthreads();
    if (keep) {
        int basec = (w == 0) ? 0 : wc[0];
        int pos = basec + __popcll(m & ((1ull << lane) - 1ull));
        sa[pos] = qa; sb[pos] = qb; sc[pos] = qc;
    }
    if (t == 0) cnt_s = wc[0] + wc[1];
    __syncthreads();
    const int cnt = cnt_s;

    const int col = tx*16 + (t & 15);
    const int row = ty*16 + (t >> 4);
    const float px = (col + 0.5f) * s - 1.0f;
    const float py = (row + 0.5f) * s - 1.0f;

    float acc = 0.0f;
    for (int k = 0; k < cnt; ++k) {
        float4 fa = sa[k];
        float4 fb = sb[k];
        float  fc = sc[k];
        float t0 = fmaf(fa.x, py, fmaf(fa.y, px, fa.z));
        float t1 = fmaf(fa.w, py, fmaf(fb.x, px, fb.y));
        float t2 = fmaf(fb.z, py, fmaf(fb.w, px, fc));
        float tmax = fmaxf(fmaxf(t0, t1), t2);
        if (__any(tmax <= TCUT)) {
            float e0 = __builtin_amdgcn_exp2f(t0);
            float e1 = __builtin_amdgcn_exp2f(t1);
            float e2 = __builtin_amdgcn_exp2f(t2);
            float Pm = (1.0f+e0) * (1.0f+e1) * (1.0f+e2);
            float prob = __builtin_amdgcn_rcpf(Pm);
            float q = fmaxf(1.0f - prob, 1e-6f);
            acc += __builtin_amdgcn_logf(q);      // log2(1-prob)
        }
    }
    part[c * NPIX + row*HH + col] = acc;          // unconditional: no zero-init
}

// ---------------- kernel 4: combine + loss reduction (VERBATIM r4) ----------
__global__ __launch_bounds__(256) void k_combine(
        const float* __restrict__ partials,
        const float* __restrict__ ref,
        float* __restrict__ out) {
    int pix = blockIdx.x * 256 + threadIdx.x;
    float tot = 0.0f;
    #pragma unroll
    for (int g = 0; g < NCHK; ++g) tot += partials[g * NPIX + pix];
    float sil = 1.0f - __builtin_amdgcn_exp2f(tot);   // 1 - exp(log_bg)
    float d = sil - ref[pix];
    float sq = d * d;
    #pragma unroll
    for (int off = 32; off > 0; off >>= 1)
        sq += __shfl_down(sq, off, 64);
    __shared__ float wsum[4];
    int wid = threadIdx.x >> 6;
    if ((threadIdx.x & 63) == 0) wsum[wid] = sq;
    __syncthreads();
    if (threadIdx.x == 0)
        atomicAdd(out, wsum[0] + wsum[1] + wsum[2] + wsum[3]);
}

extern "C" void kernel_launch(void* const* d_in, const int* in_sizes, int n_in,
                              void* d_out, int out_size, void* d_ws, size_t ws_size,
                              hipStream_t stream) {
    const float* vtx   = (const float*)d_in[0];   // (1,5000,3) f32
    const int*   faces = (const int*)  d_in[1];   // (1,1000,3) i32
    const float* cam   = (const float*)d_in[2];   // (3,) f32
    const float* ref   = (const float*)d_in[3];   // (256,256) f32
    float* out = (float*)d_out;

    char* ws = (char*)d_ws;
    unsigned* counter = (unsigned*)(ws + 0);
    float2*   xy      = (float2*)  (ws + 256);     // 40000 B
    float4*   a4      = (float4*)  (ws + 40448);   // 16000 B
    float4*   b4      = (float4*)  (ws + 56448);   // 16000 B
    float*    c1      = (float*)   (ws + 72448);   // 4000 B
    float*    part    = (float*)   (ws + 76800);   // 8*65536*4 = 2 MiB

    k_prep_vertex<<<dim3((NV+255)/256),  dim3(256), 0, stream>>>(vtx, cam, out, counter, xy);
    k_face       <<<dim3((NF+255)/256),  dim3(256), 0, stream>>>(faces, xy, a4, b4, c1);
    k_render     <<<dim3(NTILE, NCHK),   dim3(256), 0, stream>>>(a4, b4, c1, part);
    k_combine    <<<dim3(NPIX/256),      dim3(256), 0, stream>>>(part, ref, out);
}

// Round 9
// 38.583 us; speedup vs baseline: 1.7112x; 1.6355x over previous
//
#include <hip/hip_runtime.h>

#define NV 5000
#define NF 1000
#define HH 256
#define NPIX (HH*HH)
#define NTILE 256          // 16x16 tiles of 16x16 pixels
#define CS 32              // faces per chunk
#define NCHK 32            // CS*NCHK = 1024 >= NF
#define TCUT 25.0f         // exp2 cutoff: prob < 2^-25 -> negligible

// ---------------- kernel 1: vertex transform + projection (VERBATIM r1) ----
__global__ void k_prep_vertex(const float* __restrict__ vtx,
                              const float* __restrict__ cam,
                              float* __restrict__ out,
                              unsigned* __restrict__ counter,
                              float2* __restrict__ xy) {
    int i = blockIdx.x * blockDim.x + threadIdx.x;
    if (i == 0) { out[0] = 0.0f; counter[0] = 0u; }
    if (i >= NV) return;
    float ex = cam[0], ey = cam[1], ez = cam[2];
    // z_ax = normalize(-eye)
    float zn = sqrtf(ex*ex + ey*ey + ez*ez) + 1e-8f;
    float zx = -ex/zn, zy = -ey/zn, zz = -ez/zn;
    // x_ax = normalize(cross((0,1,0), z)) = normalize((zz, 0, -zx))
    float xn = sqrtf(zz*zz + zx*zx) + 1e-8f;
    float xx = zz/xn, xy_ = 0.0f, xz = -zx/xn;
    // y_ax = cross(z, x)
    float yx = zy*xz - zz*xy_;
    float yy = zz*xx - zx*xz;
    float yz = zx*xy_ - zy*xx;
    float vx = vtx[i*3+0]-ex, vy = vtx[i*3+1]-ey, vz = vtx[i*3+2]-ez;
    float cxx = vx*xx + vy*xy_ + vz*xz;
    float cyy = vx*yx + vy*yy  + vz*yz;
    float czz = vx*zx + vy*zy  + vz*zz;
    const float w = 0.5773502691896258f;   // tan(30 deg)
    float den = czz*w + 1e-8f;
    xy[i] = make_float2(cxx/den, cyy/den);
}

// ---------------- kernel 2: per-face edge coefficients (VERBATIM r1) -------
__global__ void k_face(const int* __restrict__ faces,
                       const float2* __restrict__ xy,
                       float4* __restrict__ a4,
                       float4* __restrict__ b4,
                       float* __restrict__ c1) {
    int f = blockIdx.x * blockDim.x + threadIdx.x;
    if (f >= NF) return;
    int i0 = faces[f*3+0], i1 = faces[f*3+1], i2 = faces[f*3+2];
    float2 p0 = xy[i0], p1 = xy[i1], p2 = xy[i2];
    float eax = p1.x-p0.x, eay = p1.y-p0.y;
    float ebx = p2.x-p0.x, eby = p2.y-p0.y;
    float cr = eax*eby - eay*ebx;
    float s = (cr > 0.0f) ? 1.0f : ((cr < 0.0f) ? -1.0f : 0.0f);
    const float m = -144.26950408889634f * s;   // -log2(e)/SHARP * orient

    float A0,B0,C0,A1,B1,C1,A2,B2,C2;
    {   // edge 0: p0 -> p1
        float ex_ = p1.x-p0.x, ey_ = p1.y-p0.y;
        float el = sqrtf(ex_*ex_+ey_*ey_) + 1e-8f;
        A0 = (ex_/el)*m; B0 = (-ey_/el)*m; C0 = ((ey_*p0.x - ex_*p0.y)/el)*m;
    }
    {   // edge 1: p1 -> p2
        float ex_ = p2.x-p1.x, ey_ = p2.y-p1.y;
        float el = sqrtf(ex_*ex_+ey_*ey_) + 1e-8f;
        A1 = (ex_/el)*m; B1 = (-ey_/el)*m; C1 = ((ey_*p1.x - ex_*p1.y)/el)*m;
    }
    {   // edge 2: p2 -> p0
        float ex_ = p0.x-p2.x, ey_ = p0.y-p2.y;
        float el = sqrtf(ex_*ex_+ey_*ey_) + 1e-8f;
        A2 = (ex_/el)*m; B2 = (-ey_/el)*m; C2 = ((ey_*p2.x - ex_*p2.y)/el)*m;
    }
    a4[f] = make_float4(A0, B0, C0, A1);
    b4[f] = make_float4(B1, C1, A2, B2);
    c1[f] = C2;
}

// ---- kernel 3: fused per-chunk cull + render, one (tile,chunk) per block ---
__global__ __launch_bounds__(256) void k_render(
        const float4* __restrict__ a4,
        const float4* __restrict__ b4,
        const float*  __restrict__ c1,
        float* __restrict__ part) {
    __shared__ float4 sa[CS];
    __shared__ float4 sb[CS];
    __shared__ float  sc[CS];
    __shared__ int    cnt_s;

    const int tile = blockIdx.x;
    const int c    = blockIdx.y;
    const int t    = threadIdx.x;
    const int lane = t & 63;

    const int tx = tile & 15, ty = tile >> 4;
    const float s  = 2.0f / HH;
    const float cx = (tx*16 + 8) * s - 1.0f;
    const float cy = (ty*16 + 8) * s - 1.0f;
    const float h  = 7.5f * s;

    // cull faces [c*CS, c*CS+CS): lanes 0..31 of wave 0, verbatim bound
    bool keep = false;
    float4 qa = make_float4(0,0,0,0), qb = make_float4(0,0,0,0);
    float  qc = 0.0f;
    const int f = c*CS + t;
    if (t < CS && f < NF) {
        qa = a4[f]; qb = b4[f]; qc = c1[f];
        float b0 = fmaf(qa.x, cy, fmaf(qa.y, cx, qa.z)) - (fabsf(qa.x)+fabsf(qa.y))*h;
        float b1 = fmaf(qa.w, cy, fmaf(qb.x, cx, qb.y)) - (fabsf(qa.w)+fabsf(qb.x))*h;
        float b2 = fmaf(qb.z, cy, fmaf(qb.w, cx, qc))   - (fabsf(qb.z)+fabsf(qb.w))*h;
        keep = (fmaxf(fmaxf(b0, b1), b2) <= TCUT);
    }
    unsigned long long m = __ballot(keep);    // nonzero only in wave 0
    if (keep) {
        int pos = __popcll(m & ((1ull << lane) - 1ull));
        sa[pos] = qa; sb[pos] = qb; sc[pos] = qc;
    }
    if (t == 0) cnt_s = __popcll(m);
    __syncthreads();
    const int cnt = cnt_s;

    const int col = tx*16 + (t & 15);
    const int row = ty*16 + (t >> 4);
    const float px = (col + 0.5f) * s - 1.0f;
    const float py = (row + 0.5f) * s - 1.0f;

    float acc0 = 0.0f, acc1 = 0.0f, acc2 = 0.0f, acc3 = 0.0f;
    int k = 0;
    for (; k + 4 <= cnt; k += 4) {
        float4 fa0 = sa[k+0], fb0 = sb[k+0]; float fc0 = sc[k+0];
        float4 fa1 = sa[k+1], fb1 = sb[k+1]; float fc1 = sc[k+1];
        float4 fa2 = sa[k+2], fb2 = sb[k+2]; float fc2 = sc[k+2];
        float4 fa3 = sa[k+3], fb3 = sb[k+3]; float fc3 = sc[k+3];

        float t00 = fmaf(fa0.x, py, fmaf(fa0.y, px, fa0.z));
        float t01 = fmaf(fa0.w, py, fmaf(fb0.x, px, fb0.y));
        float t02 = fmaf(fb0.z, py, fmaf(fb0.w, px, fc0));
        float t10 = fmaf(fa1.x, py, fmaf(fa1.y, px, fa1.z));
        float t11 = fmaf(fa1.w, py, fmaf(fb1.x, px, fb1.y));
        float t12 = fmaf(fb1.z, py, fmaf(fb1.w, px, fc1));
        float t20 = fmaf(fa2.x, py, fmaf(fa2.y, px, fa2.z));
        float t21 = fmaf(fa2.w, py, fmaf(fb2.x, px, fb2.y));
        float t22 = fmaf(fb2.z, py, fmaf(fb2.w, px, fc2));
        float t30 = fmaf(fa3.x, py, fmaf(fa3.y, px, fa3.z));
        float t31 = fmaf(fa3.w, py, fmaf(fb3.x, px, fb3.y));
        float t32 = fmaf(fb3.z, py, fmaf(fb3.w, px, fc3));

        float tm0 = fmaxf(fmaxf(t00, t01), t02);
        float tm1 = fmaxf(fmaxf(t10, t11), t12);
        float tm2 = fmaxf(fmaxf(t20, t21), t22);
        float tm3 = fmaxf(fmaxf(t30, t31), t32);
        float tmn = fminf(fminf(tm0, tm1), fminf(tm2, tm3));
        if (__any(tmn <= TCUT)) {
            float e00 = __builtin_amdgcn_exp2f(t00);
            float e01 = __builtin_amdgcn_exp2f(t01);
            float e02 = __builtin_amdgcn_exp2f(t02);
            float e10 = __builtin_amdgcn_exp2f(t10);
            float e11 = __builtin_amdgcn_exp2f(t11);
            float e12 = __builtin_amdgcn_exp2f(t12);
            float e20 = __builtin_amdgcn_exp2f(t20);
            float e21 = __builtin_amdgcn_exp2f(t21);
            float e22 = __builtin_amdgcn_exp2f(t22);
            float e30 = __builtin_amdgcn_exp2f(t30);
            float e31 = __builtin_amdgcn_exp2f(t31);
            float e32 = __builtin_amdgcn_exp2f(t32);
            float P0 = (1.0f+e00) * (1.0f+e01) * (1.0f+e02);
            float P1 = (1.0f+e10) * (1.0f+e11) * (1.0f+e12);
            float P2 = (1.0f+e20) * (1.0f+e21) * (1.0f+e22);
            float P3 = (1.0f+e30) * (1.0f+e31) * (1.0f+e32);
            float q0 = fmaxf(1.0f - __builtin_amdgcn_rcpf(P0), 1e-6f);
            float q1 = fmaxf(1.0f - __builtin_amdgcn_rcpf(P1), 1e-6f);
            float q2 = fmaxf(1.0f - __builtin_amdgcn_rcpf(P2), 1e-6f);
            float q3 = fmaxf(1.0f - __builtin_amdgcn_rcpf(P3), 1e-6f);
            acc0 += __builtin_amdgcn_logf(q0);
            acc1 += __builtin_amdgcn_logf(q1);
            acc2 += __builtin_amdgcn_logf(q2);
            acc3 += __builtin_amdgcn_logf(q3);
        }
    }
    for (; k < cnt; ++k) {
        float4 fa = sa[k];
        float4 fb = sb[k];
        float  fc = sc[k];
        float t0 = fmaf(fa.x, py, fmaf(fa.y, px, fa.z));
        float t1 = fmaf(fa.w, py, fmaf(fb.x, px, fb.y));
        float t2 = fmaf(fb.z, py, fmaf(fb.w, px, fc));
        float tmax = fmaxf(fmaxf(t0, t1), t2);
        if (__any(tmax <= TCUT)) {
            float e0 = __builtin_amdgcn_exp2f(t0);
            float e1 = __builtin_amdgcn_exp2f(t1);
            float e2 = __builtin_amdgcn_exp2f(t2);
            float Pm = (1.0f+e0) * (1.0f+e1) * (1.0f+e2);
            float prob = __builtin_amdgcn_rcpf(Pm);
            float q = fmaxf(1.0f - prob, 1e-6f);
            acc0 += __builtin_amdgcn_logf(q);
        }
    }
    part[c * NPIX + row*HH + col] = (acc0 + acc1) + (acc2 + acc3);
}

// ---------------- kernel 4: combine + loss reduction ------------------------
__global__ __launch_bounds__(256) void k_combine(
        const float* __restrict__ partials,
        const float* __restrict__ ref,
        float* __restrict__ out) {
    int pix = blockIdx.x * 256 + threadIdx.x;
    float tot = 0.0f;
    #pragma unroll
    for (int g = 0; g < NCHK; ++g) tot += partials[g * NPIX + pix];
    float sil = 1.0f - __builtin_amdgcn_exp2f(tot);   // 1 - exp(log_bg)
    float d = sil - ref[pix];
    float sq = d * d;
    #pragma unroll
    for (int off = 32; off > 0; off >>= 1)
        sq += __shfl_down(sq, off, 64);
    __shared__ float wsum[4];
    int wid = threadIdx.x >> 6;
    if ((threadIdx.x & 63) == 0) wsum[wid] = sq;
    __syncthreads();
    if (threadIdx.x == 0)
        atomicAdd(out, wsum[0] + wsum[1] + wsum[2] + wsum[3]);
}

extern "C" void kernel_launch(void* const* d_in, const int* in_sizes, int n_in,
                              void* d_out, int out_size, void* d_ws, size_t ws_size,
                              hipStream_t stream) {
    const float* vtx   = (const float*)d_in[0];   // (1,5000,3) f32
    const int*   faces = (const int*)  d_in[1];   // (1,1000,3) i32
    const float* cam   = (const float*)d_in[2];   // (3,) f32
    const float* ref   = (const float*)d_in[3];   // (256,256) f32
    float* out = (float*)d_out;

    char* ws = (char*)d_ws;
    unsigned* counter = (unsigned*)(ws + 0);
    float2*   xy      = (float2*)  (ws + 256);     // 40000 B
    float4*   a4      = (float4*)  (ws + 40448);   // 16000 B
    float4*   b4      = (float4*)  (ws + 56448);   // 16000 B
    float*    c1      = (float*)   (ws + 72448);   // 4000 B
    float*    part    = (float*)   (ws + 76800);   // 32*65536*4 = 8 MiB

    k_prep_vertex<<<dim3((NV+255)/256),  dim3(256), 0, stream>>>(vtx, cam, out, counter, xy);
    k_face       <<<dim3((NF+255)/256),  dim3(256), 0, stream>>>(faces, xy, a4, b4, c1);
    k_render     <<<dim3(NTILE, NCHK),   dim3(256), 0, stream>>>(a4, b4, c1, part);
    k_combine    <<<dim3(NPIX/256),      dim3(256), 0, stream>>>(part, ref, out);
}